// Round 9
// baseline (340.585 us; speedup 1.0000x reference)
//
#include <hip/hip_runtime.h>

#define N_NODES 100000
#define N_EDGES 1600000
#define D 128
#define N_TILES 3125        // N_NODES / 32
#define GEMM_GRID 512
#define BK_NODES 256        // nodes per bucket
#define N_BUCKETS 391       // ceil(N_NODES / BK_NODES)
#define BKT_CAP 5120        // per-bucket slot capacity (mean 4092, std 64 -> 16 sigma)
#define SC_BLOCKS 128
#define EPB 12500           // edges per scatter block (N_EDGES / SC_BLOCKS)

typedef _Float16 f16;
typedef _Float16 f16x8 __attribute__((ext_vector_type(8)));
typedef _Float16 f16x2 __attribute__((ext_vector_type(2)));
typedef float f32x4 __attribute__((ext_vector_type(4)));

// ---------------- CSR build (bucket-based, no per-node global atomics) ----------------

// pass 1: block-local bucket scatter. LDS histogram -> ONE global atomic per
// (block,bucket) reservation (chain length = SC_BLOCKS) -> LDS-cursor placement
// into fixed-capacity bucket slots. Afterwards bcur[b] == bucket edge count.
__global__ __launch_bounds__(256) void bucket_scatter(const int* __restrict__ src,
                                                      const int* __restrict__ dst,
                                                      const float* __restrict__ w,
                                                      int* __restrict__ bcur,
                                                      int2* __restrict__ bkt) {
    __shared__ int hist[N_BUCKETS];
    __shared__ int base[N_BUCKETS];
    int tid = threadIdx.x;
    int v0  = blockIdx.x * (EPB / 4);        // int4-chunk base
    const int4*   dst4 = (const int4*)dst;
    const int4*   src4 = (const int4*)src;
    const float4* w4   = (const float4*)w;

    for (int b = tid; b < N_BUCKETS; b += 256) hist[b] = 0;
    __syncthreads();

    // phase A: count buckets (vectorized dst reads)
    for (int v = tid; v < EPB / 4; v += 256) {
        int4 d = dst4[v0 + v];
        atomicAdd(&hist[d.x >> 8], 1);
        atomicAdd(&hist[d.y >> 8], 1);
        atomicAdd(&hist[d.z >> 8], 1);
        atomicAdd(&hist[d.w >> 8], 1);
    }
    __syncthreads();

    // phase B: reserve within-bucket ranges (bcur starts at 0)
    for (int b = tid; b < N_BUCKETS; b += 256) {
        int c = hist[b];
        base[b] = b * BKT_CAP + ((c > 0) ? atomicAdd(&bcur[b], c) : 0);
        hist[b] = 0;
    }
    __syncthreads();

    // phase C: place edges densely inside reserved ranges
    for (int v = tid; v < EPB / 4; v += 256) {
        int4   d = dst4[v0 + v];
        int4   s = src4[v0 + v];
        float4 f = w4[v0 + v];
        {
            int p = base[d.x >> 8] + atomicAdd(&hist[d.x >> 8], 1);
            unsigned wq = (unsigned)rintf(f.x * 32767.0f);
            bkt[p] = make_int2(s.x, (int)(((unsigned)d.x << 15) | wq));
        }
        {
            int p = base[d.y >> 8] + atomicAdd(&hist[d.y >> 8], 1);
            unsigned wq = (unsigned)rintf(f.y * 32767.0f);
            bkt[p] = make_int2(s.y, (int)(((unsigned)d.y << 15) | wq));
        }
        {
            int p = base[d.z >> 8] + atomicAdd(&hist[d.z >> 8], 1);
            unsigned wq = (unsigned)rintf(f.z * 32767.0f);
            bkt[p] = make_int2(s.z, (int)(((unsigned)d.z << 15) | wq));
        }
        {
            int p = base[d.w >> 8] + atomicAdd(&hist[d.w >> 8], 1);
            unsigned wq = (unsigned)rintf(f.w * 32767.0f);
            bkt[p] = make_int2(s.w, (int)(((unsigned)d.w << 15) | wq));
        }
    }
}

// exclusive scan over the 391 bucket counts -> bucket CSR bases (one block)
__global__ __launch_bounds__(512) void bucket_scan(const int* __restrict__ bcnt,
                                                   int* __restrict__ bbase) {
    __shared__ int sc[512];
    int tid = threadIdx.x;
    int v = (tid < N_BUCKETS) ? bcnt[tid] : 0;
    sc[tid] = v;
    __syncthreads();
    for (int off = 1; off < 512; off <<= 1) {
        int t = (tid >= off) ? sc[tid - off] : 0;
        __syncthreads();
        sc[tid] += t;
        __syncthreads();
    }
    if (tid < N_BUCKETS) bbase[tid] = sc[tid] - v;
}

// pass 2: one block per bucket. LDS node histogram + block scan -> row_ptr AND
// final placement. csr_s[p] = src; csr_w[p] = w (f32, ready for fma via readlane).
__global__ __launch_bounds__(256) void bucket_finalize(const int* __restrict__ bcnt,
                                                       const int* __restrict__ bbase,
                                                       const int2* __restrict__ bkt,
                                                       unsigned* __restrict__ csr_s,
                                                       float* __restrict__ csr_w,
                                                       int* __restrict__ row_ptr) {
    __shared__ int ncnt[BK_NODES];
    __shared__ int noff[BK_NODES];
    __shared__ int sc[BK_NODES];
    int tid   = threadIdx.x;
    int b     = blockIdx.x;
    int node0 = b * BK_NODES;
    int cnt   = bcnt[b];
    int base  = bbase[b];
    int e0    = b * BKT_CAP;

    ncnt[tid] = 0;
    __syncthreads();
    for (int i = tid; i < cnt; i += 256) {
        int local = (int)((unsigned)bkt[e0 + i].y >> 15) - node0;
        atomicAdd(&ncnt[local], 1);
    }
    __syncthreads();
    // exclusive scan of ncnt
    int s = ncnt[tid];
    sc[tid] = s;
    __syncthreads();
    for (int off = 1; off < 256; off <<= 1) {
        int t = (tid >= off) ? sc[tid - off] : 0;
        __syncthreads();
        sc[tid] += t;
        __syncthreads();
    }
    noff[tid] = sc[tid] - s;
    ncnt[tid] = 0;   // reuse as placement cursor
    {
        int nN = N_NODES - node0; if (nN > BK_NODES) nN = BK_NODES;
        if (tid < nN) row_ptr[node0 + tid] = base + noff[tid];
        if (b == N_BUCKETS - 1 && tid == 0) row_ptr[N_NODES] = N_EDGES;
    }
    __syncthreads();
    for (int i = tid; i < cnt; i += 256) {
        int2 t = bkt[e0 + i];
        unsigned meta = (unsigned)t.y;
        int local = (int)(meta >> 15) - node0;
        int p = base + noff[local] + atomicAdd(&ncnt[local], 1);
        csr_s[p] = (unsigned)t.x;
        csr_w[p] = (float)(meta & 0x7fffu) * (1.0f / 32767.0f);
    }
}

// ---------------- fp32 -> f16 convert (x only, once) ----------------

__global__ __launch_bounds__(256) void cvt_f32_f16(const float* __restrict__ in,
                                                   f16* __restrict__ out) {
    int i = blockIdx.x * 256 + threadIdx.x;   // grid 6250: 8 elems/thread
    const float4* in4 = (const float4*)in;
    float4 a = in4[i * 2], b = in4[i * 2 + 1];
    f16x8 v;
    v[0] = (f16)a.x; v[1] = (f16)a.y; v[2] = (f16)a.z; v[3] = (f16)a.w;
    v[4] = (f16)b.x; v[5] = (f16)b.y; v[6] = (f16)b.z; v[7] = (f16)b.w;
    ((f16x8*)out)[i] = v;
}

// ---------------- weight pack: B-fragment layout, f16 ----------------
// Bp element ((ks*8 + ct)*64 + lane)*8 + e = W[j][k] with
// j = ct*16 + (lane&15), k = ks*32 + (lane>>4)*8 + e  (k<128 -> Wrel, else Wroot)

__global__ __launch_bounds__(256) void pack_weights(const float* __restrict__ Wrel,
                                                    const float* __restrict__ Wroot,
                                                    f16* __restrict__ Bp) {
    int idx = blockIdx.x * 256 + threadIdx.x;   // 32768 total -> 128 blocks
    int e = idx & 7, lane = (idx >> 3) & 63, ct = (idx >> 9) & 7, ks = idx >> 12;
    int j = ct * 16 + (lane & 15);
    int k = ks * 32 + (lane >> 4) * 8 + e;
    float w = (k < D) ? Wrel[j * D + k] : Wroot[j * D + (k - D)];
    Bp[idx] = (f16)w;
}

// ---------------- aggregation: one wave/node, readlane CSR, pinned 16-deep MLP ----
// csr_s: uniform src ids (readlane -> SGPR saddr). csr_w: f32 weights
// (readlane -> SGPR fma operand, zero decode VALU). Tail SKIPS (uniform
// branches), never clamps -> no wasted gathers.

__global__ __launch_bounds__(256) void aggregate_kernel(const f16* __restrict__ h,
                                                        const int* __restrict__ row_ptr,
                                                        const unsigned* __restrict__ csr_s,
                                                        const float* __restrict__ csr_w,
                                                        f16* __restrict__ agg) {
    int node = blockIdx.x * 4 + (threadIdx.x >> 6);   // grid*4 == N_NODES exactly
    int lane = threadIdx.x & 63;
    int li   = lane & 15;
    int beg = row_ptr[node], end = row_ptr[node + 1];
    const f16x2* h2 = (const f16x2*)h;   // lane covers channels 2l, 2l+1

    float ax0 = 0.f, ay0 = 0.f, ax1 = 0.f, ay1 = 0.f;

    int e = beg;
    for (; e + 16 <= end; e += 16) {
        // lanes 0-15 fetch 16 src ids + 16 f32 weights (uniform 64B lines)
        unsigned pv = csr_s[e + li];
        float    wv = csr_w[e + li];
        __builtin_amdgcn_sched_barrier(0);
        f16x2 gv[16];
        float gw[16];
#pragma unroll
        for (int k = 0; k < 16; ++k) {
            unsigned s = __builtin_amdgcn_readlane(pv, k);   // uniform -> SGPR
            gw[k] = __int_as_float(__builtin_amdgcn_readlane(__float_as_int(wv), k));
            gv[k] = h2[(size_t)s * 64 + lane];               // saddr gather, 256B/wave
        }
        __builtin_amdgcn_sched_barrier(0);   // keep all 16 gathers in flight
#pragma unroll
        for (int k = 0; k < 16; ++k) {
            float vx = (float)gv[k][0], vy = (float)gv[k][1];
            if (k & 1) { ax1 = fmaf(gw[k], vx, ax1); ay1 = fmaf(gw[k], vy, ay1); }
            else       { ax0 = fmaf(gw[k], vx, ax0); ay0 = fmaf(gw[k], vy, ay0); }
        }
    }
    if (e < end) {   // tail: rem is wave-uniform -> guards are uniform branches
        int rem = end - e;                    // 1..15
        unsigned pv = 0; float wv = 0.f;
        if (li < rem) { pv = csr_s[e + li]; wv = csr_w[e + li]; }
        __builtin_amdgcn_sched_barrier(0);
        f16x2 gv[16];
        float gw[16];
#pragma unroll
        for (int k = 0; k < 16; ++k) {
            if (k < rem) {
                unsigned s = __builtin_amdgcn_readlane(pv, k);
                gw[k] = __int_as_float(__builtin_amdgcn_readlane(__float_as_int(wv), k));
                gv[k] = h2[(size_t)s * 64 + lane];
            }
        }
        __builtin_amdgcn_sched_barrier(0);
#pragma unroll
        for (int k = 0; k < 16; ++k) {
            if (k < rem) {
                float vx = (float)gv[k][0], vy = (float)gv[k][1];
                if (k & 1) { ax1 = fmaf(gw[k], vx, ax1); ay1 = fmaf(gw[k], vy, ay1); }
                else       { ax0 = fmaf(gw[k], vx, ax0); ay0 = fmaf(gw[k], vy, ay0); }
            }
        }
    }
    f16x2 o;
    o[0] = (f16)(ax0 + ax1);
    o[1] = (f16)(ay0 + ay1);
    ((f16x2*)agg)[(size_t)node * 64 + lane] = o;
}

// ---------------- MFMA GEMM: out = [agg|h] @ Bp + bias (+ReLU) ----------------
// 256 thr = 4 waves (2 row x 2 col). Wave owns 16 rows x 64 cols.
// B-frags in registers. A (f16) staged in LDS, XOR-swizzled, double-buffered.
// FINAL=0: f16 out + ReLU.  FINAL=1: fp32 out, no ReLU.

template <int FINAL>
__global__ __launch_bounds__(256, 2) void gemm_mfma(const f16* __restrict__ agg,
                                                    const f16* __restrict__ h,
                                                    const f16x8* __restrict__ Bp,
                                                    const float* __restrict__ bias,
                                                    void* __restrict__ outp) {
    __shared__ f16 sA[2][32 * 256];   // 2 x 16 KB
    int tid  = threadIdx.x;
    int lane = tid & 63;
    int wid  = tid >> 6;
    int wrow = wid >> 1;              // rows [wrow*16, +16)
    int wcol = wid & 1;               // cols [wcol*64, +64)

    // B fragments: 8 k-steps x 4 col-tiles, loaded once (L2-hot)
    f16x8 breg[8][4];
#pragma unroll
    for (int ks = 0; ks < 8; ++ks)
#pragma unroll
        for (int c = 0; c < 4; ++c)
            breg[ks][c] = Bp[(ks * 8 + wcol * 4 + c) * 64 + lane];

    float bv[4];
#pragma unroll
    for (int c = 0; c < 4; ++c) bv[c] = bias[wcol * 64 + c * 16 + (lane & 15)];

    const uint4* a16 = (const uint4*)agg;   // 8 f16 per uint4; 16 chunks/row
    const uint4* h16 = (const uint4*)h;

    // prologue: stage first tile into buf 0 (1024 x 16B chunks, 4 iters)
    {
        int row0 = blockIdx.x * 32;
#pragma unroll
        for (int it = 0; it < 4; ++it) {
            int i = it * 256 + tid, r = i >> 5, c8 = i & 31;
            uint4 v = (c8 < 16) ? a16[(row0 + r) * 16 + c8]
                                : h16[(row0 + r) * 16 + (c8 - 16)];
            int o = (r * 256 + c8 * 8) ^ ((r & 7) << 3);
            *(uint4*)&sA[0][o] = v;
        }
    }
    __syncthreads();

    int buf = 0;
    for (int t = blockIdx.x; t < N_TILES; t += GEMM_GRID) {
        int  tn = t + GEMM_GRID;
        bool havenext = (tn < N_TILES);

        // issue next tile's global loads early (latency hides under MFMA)
        uint4 sreg[4];
        if (havenext) {
            int row0 = tn * 32;
#pragma unroll
            for (int it = 0; it < 4; ++it) {
                int i = it * 256 + tid, r = i >> 5, c8 = i & 31;
                sreg[it] = (c8 < 16) ? a16[(row0 + r) * 16 + c8]
                                     : h16[(row0 + r) * 16 + (c8 - 16)];
            }
        }

        // compute tile t from sA[buf]
        f32x4 acc[4] = {f32x4{0,0,0,0}, f32x4{0,0,0,0}, f32x4{0,0,0,0}, f32x4{0,0,0,0}};
        int arow = wrow * 16 + (lane & 15);
        int kg   = (lane >> 4) * 8;
#pragma unroll
        for (int ks = 0; ks < 8; ++ks) {
            int o = (arow * 256 + ks * 32 + kg) ^ ((arow & 7) << 3);
            f16x8 afrag = *(const f16x8*)&sA[buf][o];
#pragma unroll
            for (int c = 0; c < 4; ++c)
                acc[c] = __builtin_amdgcn_mfma_f32_16x16x32_f16(afrag, breg[ks][c],
                                                                acc[c], 0, 0, 0);
        }

        // epilogue: bias (+relu), store C  (C/D map: col=lane&15, row=(lane>>4)*4+r)
        {
            int row0 = t * 32;
#pragma unroll
            for (int c = 0; c < 4; ++c) {
                int col = wcol * 64 + c * 16 + (lane & 15);
#pragma unroll
                for (int r = 0; r < 4; ++r) {
                    int row = row0 + wrow * 16 + (lane >> 4) * 4 + r;
                    float o = acc[c][r] + bv[c];
                    if (FINAL) {
                        ((float*)outp)[(size_t)row * D + col] = o;
                    } else {
                        ((f16*)outp)[(size_t)row * D + col] = (f16)fmaxf(o, 0.f);
                    }
                }
            }
        }

        __syncthreads();   // all waves done reading sA[buf^1] (previous iter)
        if (havenext) {
#pragma unroll
            for (int it = 0; it < 4; ++it) {
                int i = it * 256 + tid, r = i >> 5, c8 = i & 31;
                int o = (r * 256 + c8 * 8) ^ ((r & 7) << 3);
                *(uint4*)&sA[buf ^ 1][o] = sreg[it];
            }
        }
        __syncthreads();
        buf ^= 1;
    }
}

// ---------------- launch ----------------

extern "C" void kernel_launch(void* const* d_in, const int* in_sizes, int n_in,
                              void* d_out, int out_size, void* d_ws, size_t ws_size,
                              hipStream_t stream) {
    const float* x  = (const float*)d_in[0];
    const float* ew = (const float*)d_in[1];
    const float* W_rel[3]  = {(const float*)d_in[2], (const float*)d_in[5], (const float*)d_in[8]};
    const float* W_root[3] = {(const float*)d_in[3], (const float*)d_in[6], (const float*)d_in[9]};
    const float* bias[3]   = {(const float*)d_in[4], (const float*)d_in[7], (const float*)d_in[10]};
    const int* esrc = (const int*)d_in[11];
    const int* edst = (const int*)d_in[12];

    char* ws = (char*)d_ws;
    f16*      agg16   = (f16*)     (ws);                // 25,600,000 B
    f16*      bufA    = (f16*)     (ws + 25600000);     // 25,600,000 B
    f16*      bufB    = (f16*)     (ws + 51200000);     // 25,600,000 B
    unsigned* csr_s   = (unsigned*)(ws + 76800000);     //  6,400,000 B
    float*    csr_w   = (float*)   (ws + 83200000);     //  6,400,000 B
    int2*     bkt     = (int2*)    (ws + 89600000);     // 16,015,360 B (391 x 5120 x 8)
    int*      row_ptr = (int*)     (ws + 105615360);    //    400,016 B
    int*      bcur    = (int*)     (ws + 106015376);    //      1,564 B
    int*      bbase   = (int*)     (ws + 106016940);    //      1,564 B
    f16*      Bp      = (f16*)     (ws + 106018504);    //    196,608 B

    // CSR build (bucket-based; reused by all 3 layers)
    hipMemsetAsync(bcur, 0, N_BUCKETS * sizeof(int), stream);
    bucket_scatter<<<SC_BLOCKS, 256, 0, stream>>>(esrc, edst, ew, bcur, bkt);
    bucket_scan<<<1, 512, 0, stream>>>(bcur, bbase);
    bucket_finalize<<<N_BUCKETS, 256, 0, stream>>>(bcur, bbase, bkt, csr_s, csr_w, row_ptr);

    // x -> f16, weight packs
    cvt_f32_f16<<<6250, 256, 0, stream>>>(x, bufA);
    for (int l = 0; l < 3; ++l)
        pack_weights<<<128, 256, 0, stream>>>(W_rel[l], W_root[l], Bp + l * 32768);

    // layer 0: bufA -> bufB (f16, relu)
    aggregate_kernel<<<N_NODES / 4, 256, 0, stream>>>(bufA, row_ptr, csr_s, csr_w, agg16);
    gemm_mfma<0><<<GEMM_GRID, 256, 0, stream>>>(agg16, bufA, (const f16x8*)(Bp + 0 * 32768),
                                                bias[0], bufB);
    // layer 1: bufB -> bufA (f16, relu)
    aggregate_kernel<<<N_NODES / 4, 256, 0, stream>>>(bufB, row_ptr, csr_s, csr_w, agg16);
    gemm_mfma<0><<<GEMM_GRID, 256, 0, stream>>>(agg16, bufB, (const f16x8*)(Bp + 1 * 32768),
                                                bias[1], bufA);
    // layer 2: bufA -> d_out (fp32, no relu)
    aggregate_kernel<<<N_NODES / 4, 256, 0, stream>>>(bufA, row_ptr, csr_s, csr_w, agg16);
    gemm_mfma<1><<<GEMM_GRID, 256, 0, stream>>>(agg16, bufA, (const f16x8*)(Bp + 2 * 32768),
                                                bias[2], d_out);
}

// Round 10
// 314.983 us; speedup vs baseline: 1.0813x; 1.0813x over previous
//
#include <hip/hip_runtime.h>

#define N_NODES 100000
#define N_EDGES 1600000
#define D 128
#define N_TILES 3125        // N_NODES / 32
#define GEMM_GRID 512
#define BK_NODES 256        // nodes per bucket
#define N_BUCKETS 391       // ceil(N_NODES / BK_NODES)
#define BKT_CAP 5120        // per-bucket slot capacity (mean 4092, std 64 -> 16 sigma)
#define SC_BLOCKS 128
#define EPB 12500           // edges per scatter block (N_EDGES / SC_BLOCKS)

typedef _Float16 f16;
typedef _Float16 f16x8 __attribute__((ext_vector_type(8)));
typedef _Float16 f16x2 __attribute__((ext_vector_type(2)));
typedef float f32x4 __attribute__((ext_vector_type(4)));

// f16 bit pattern of w in [0,1] fits in 15 bits (max 0x3C00 = 1.0)
__device__ __forceinline__ unsigned f16bits(float x) {
    union { f16 h; unsigned short u; } c;
    c.h = (f16)x;
    return (unsigned)c.u;
}

// ---------------- CSR build (bucket-based, no per-node global atomics) ----------------

// pass 1: block-local bucket scatter. LDS histogram -> ONE global atomic per
// (block,bucket) reservation (chain length = SC_BLOCKS) -> LDS-cursor placement
// into fixed-capacity bucket slots. Afterwards bcur[b] == bucket edge count.
__global__ __launch_bounds__(256) void bucket_scatter(const int* __restrict__ src,
                                                      const int* __restrict__ dst,
                                                      const float* __restrict__ w,
                                                      int* __restrict__ bcur,
                                                      int2* __restrict__ bkt) {
    __shared__ int hist[N_BUCKETS];
    __shared__ int base[N_BUCKETS];
    int tid = threadIdx.x;
    int v0  = blockIdx.x * (EPB / 4);        // int4-chunk base
    const int4*   dst4 = (const int4*)dst;
    const int4*   src4 = (const int4*)src;
    const float4* w4   = (const float4*)w;

    for (int b = tid; b < N_BUCKETS; b += 256) hist[b] = 0;
    __syncthreads();

    // phase A: count buckets (vectorized dst reads)
    for (int v = tid; v < EPB / 4; v += 256) {
        int4 d = dst4[v0 + v];
        atomicAdd(&hist[d.x >> 8], 1);
        atomicAdd(&hist[d.y >> 8], 1);
        atomicAdd(&hist[d.z >> 8], 1);
        atomicAdd(&hist[d.w >> 8], 1);
    }
    __syncthreads();

    // phase B: reserve within-bucket ranges (bcur starts at 0)
    for (int b = tid; b < N_BUCKETS; b += 256) {
        int c = hist[b];
        base[b] = b * BKT_CAP + ((c > 0) ? atomicAdd(&bcur[b], c) : 0);
        hist[b] = 0;
    }
    __syncthreads();

    // phase C: place edges densely inside reserved ranges (meta = dst<<15 | f16(w))
    for (int v = tid; v < EPB / 4; v += 256) {
        int4   d = dst4[v0 + v];
        int4   s = src4[v0 + v];
        float4 f = w4[v0 + v];
        {
            int p = base[d.x >> 8] + atomicAdd(&hist[d.x >> 8], 1);
            bkt[p] = make_int2(s.x, (int)(((unsigned)d.x << 15) | f16bits(f.x)));
        }
        {
            int p = base[d.y >> 8] + atomicAdd(&hist[d.y >> 8], 1);
            bkt[p] = make_int2(s.y, (int)(((unsigned)d.y << 15) | f16bits(f.y)));
        }
        {
            int p = base[d.z >> 8] + atomicAdd(&hist[d.z >> 8], 1);
            bkt[p] = make_int2(s.z, (int)(((unsigned)d.z << 15) | f16bits(f.z)));
        }
        {
            int p = base[d.w >> 8] + atomicAdd(&hist[d.w >> 8], 1);
            bkt[p] = make_int2(s.w, (int)(((unsigned)d.w << 15) | f16bits(f.w)));
        }
    }
}

// exclusive scan over the 391 bucket counts -> bucket CSR bases (one block)
__global__ __launch_bounds__(512) void bucket_scan(const int* __restrict__ bcnt,
                                                   int* __restrict__ bbase) {
    __shared__ int sc[512];
    int tid = threadIdx.x;
    int v = (tid < N_BUCKETS) ? bcnt[tid] : 0;
    sc[tid] = v;
    __syncthreads();
    for (int off = 1; off < 512; off <<= 1) {
        int t = (tid >= off) ? sc[tid - off] : 0;
        __syncthreads();
        sc[tid] += t;
        __syncthreads();
    }
    if (tid < N_BUCKETS) bbase[tid] = sc[tid] - v;
}

// pass 2: one block per bucket. LDS node histogram + block scan -> row_ptr AND
// final csr placement (dense contiguous writes). csr[p] = (src << 15) | f16(w).
__global__ __launch_bounds__(256) void bucket_finalize(const int* __restrict__ bcnt,
                                                       const int* __restrict__ bbase,
                                                       const int2* __restrict__ bkt,
                                                       unsigned* __restrict__ csr,
                                                       int* __restrict__ row_ptr) {
    __shared__ int ncnt[BK_NODES];
    __shared__ int noff[BK_NODES];
    __shared__ int sc[BK_NODES];
    int tid   = threadIdx.x;
    int b     = blockIdx.x;
    int node0 = b * BK_NODES;
    int cnt   = bcnt[b];
    int base  = bbase[b];
    int e0    = b * BKT_CAP;

    ncnt[tid] = 0;
    __syncthreads();
    for (int i = tid; i < cnt; i += 256) {
        int local = (int)((unsigned)bkt[e0 + i].y >> 15) - node0;
        atomicAdd(&ncnt[local], 1);
    }
    __syncthreads();
    // exclusive scan of ncnt
    int s = ncnt[tid];
    sc[tid] = s;
    __syncthreads();
    for (int off = 1; off < 256; off <<= 1) {
        int t = (tid >= off) ? sc[tid - off] : 0;
        __syncthreads();
        sc[tid] += t;
        __syncthreads();
    }
    noff[tid] = sc[tid] - s;
    ncnt[tid] = 0;   // reuse as placement cursor
    {
        int nN = N_NODES - node0; if (nN > BK_NODES) nN = BK_NODES;
        if (tid < nN) row_ptr[node0 + tid] = base + noff[tid];
        if (b == N_BUCKETS - 1 && tid == 0) row_ptr[N_NODES] = N_EDGES;
    }
    __syncthreads();
    for (int i = tid; i < cnt; i += 256) {
        int2 t = bkt[e0 + i];
        unsigned meta = (unsigned)t.y;
        int local = (int)(meta >> 15) - node0;
        int p = base + noff[local] + atomicAdd(&ncnt[local], 1);
        csr[p] = ((unsigned)t.x << 15) | (meta & 0x7fffu);
    }
}

// ---------------- fp32 -> f16 convert (x only, once) ----------------

__global__ __launch_bounds__(256) void cvt_f32_f16(const float* __restrict__ in,
                                                   f16* __restrict__ out) {
    int i = blockIdx.x * 256 + threadIdx.x;   // grid 6250: 8 elems/thread
    const float4* in4 = (const float4*)in;
    float4 a = in4[i * 2], b = in4[i * 2 + 1];
    f16x8 v;
    v[0] = (f16)a.x; v[1] = (f16)a.y; v[2] = (f16)a.z; v[3] = (f16)a.w;
    v[4] = (f16)b.x; v[5] = (f16)b.y; v[6] = (f16)b.z; v[7] = (f16)b.w;
    ((f16x8*)out)[i] = v;
}

// ---------------- weight pack: B-fragment layout, f16 ----------------
// Bp element ((ks*8 + ct)*64 + lane)*8 + e = W[j][k] with
// j = ct*16 + (lane&15), k = ks*32 + (lane>>4)*8 + e  (k<128 -> Wrel, else Wroot)

__global__ __launch_bounds__(256) void pack_weights(const float* __restrict__ Wrel,
                                                    const float* __restrict__ Wroot,
                                                    f16* __restrict__ Bp) {
    int idx = blockIdx.x * 256 + threadIdx.x;   // 32768 total -> 128 blocks
    int e = idx & 7, lane = (idx >> 3) & 63, ct = (idx >> 9) & 7, ks = idx >> 12;
    int j = ct * 16 + (lane & 15);
    int k = ks * 32 + (lane >> 4) * 8 + e;
    float w = (k < D) ? Wrel[j * D + k] : Wroot[j * D + (k - D)];
    Bp[idx] = (f16)w;
}

// ---------------- aggregation: one wave/node, readlane CSR, pk_fma f16 ----------------
// csr word = (src<<15) | f16bits(w). Decode is pure SALU on the readlane result;
// per-edge VALU = 1 readlane + 1 v_pk_fma_f16. Tail CLAMPS (duplicate-address
// gathers broadcast-coalesce to one line: memory-free) with weight forced to 0.

__global__ __launch_bounds__(256) void aggregate_kernel(const f16* __restrict__ h,
                                                        const int* __restrict__ row_ptr,
                                                        const unsigned* __restrict__ csr,
                                                        f16* __restrict__ agg) {
    int node = blockIdx.x * 4 + (threadIdx.x >> 6);   // grid*4 == N_NODES exactly
    int lane = threadIdx.x & 63;
    int li   = lane & 15;
    int beg = row_ptr[node], end = row_ptr[node + 1];
    const f16x2* h2 = (const f16x2*)h;   // lane covers channels 2l, 2l+1

    f16x2 acc0 = {(f16)0.f, (f16)0.f};
    f16x2 acc1 = {(f16)0.f, (f16)0.f};

    int e = beg;
    for (; e + 16 <= end; e += 16) {
        // lanes 0-15 fetch 16 packed edges in one 64B line (quarters duplicate)
        unsigned pv = csr[e + li];
        __builtin_amdgcn_sched_barrier(0);
        f16x2    gv[16];
        unsigned wm[16];
#pragma unroll
        for (int k = 0; k < 16; ++k) {
            unsigned s = __builtin_amdgcn_readlane(pv, k);   // uniform -> SGPR
            wm[k] = s & 0x7fffu;                             // f16 bits of w (SALU)
            gv[k] = h2[(size_t)(s >> 15) * 64 + lane];       // saddr gather, 256B/wave
        }
        __builtin_amdgcn_sched_barrier(0);   // keep all 16 gathers in flight
#pragma unroll
        for (int k = 0; k < 16; ++k) {
            union { unsigned u; f16x2 v; } wc;
            wc.u = wm[k] * 0x10001u;         // duplicate f16 into both halves (SALU)
            if (k & 1) acc1 += gv[k] * wc.v; // v_pk_fma_f16
            else       acc0 += gv[k] * wc.v;
        }
    }
    if (e < end) {   // clamped tail: dead lanes re-read one line (broadcast), w=0
        int rem = end - e;                   // 1..15
        int idx = e + li, em1 = end - 1;
        idx = idx < em1 ? idx : em1;
        unsigned pv = csr[idx];
        __builtin_amdgcn_sched_barrier(0);
        f16x2    gv[16];
        unsigned wm[16];
#pragma unroll
        for (int k = 0; k < 16; ++k) {
            unsigned s = __builtin_amdgcn_readlane(pv, k);
            s = (k < rem) ? s : 0u;          // wave-uniform select (SALU)
            wm[k] = s & 0x7fffu;
            gv[k] = h2[(size_t)(s >> 15) * 64 + lane];
        }
        __builtin_amdgcn_sched_barrier(0);
#pragma unroll
        for (int k = 0; k < 16; ++k) {
            union { unsigned u; f16x2 v; } wc;
            wc.u = wm[k] * 0x10001u;
            if (k & 1) acc1 += gv[k] * wc.v;
            else       acc0 += gv[k] * wc.v;
        }
    }
    ((f16x2*)agg)[(size_t)node * 64 + lane] = acc0 + acc1;
}

// ---------------- MFMA GEMM: out = [agg|h] @ Bp + bias (+ReLU) ----------------
// 256 thr = 4 waves (2 row x 2 col). Wave owns 16 rows x 64 cols.
// B-frags in registers. A (f16) staged in LDS, XOR-swizzled, double-buffered.
// FINAL=0: f16 out + ReLU.  FINAL=1: fp32 out, no ReLU.

template <int FINAL>
__global__ __launch_bounds__(256, 2) void gemm_mfma(const f16* __restrict__ agg,
                                                    const f16* __restrict__ h,
                                                    const f16x8* __restrict__ Bp,
                                                    const float* __restrict__ bias,
                                                    void* __restrict__ outp) {
    __shared__ f16 sA[2][32 * 256];   // 2 x 16 KB
    int tid  = threadIdx.x;
    int lane = tid & 63;
    int wid  = tid >> 6;
    int wrow = wid >> 1;              // rows [wrow*16, +16)
    int wcol = wid & 1;               // cols [wcol*64, +64)

    // B fragments: 8 k-steps x 4 col-tiles, loaded once (L2-hot)
    f16x8 breg[8][4];
#pragma unroll
    for (int ks = 0; ks < 8; ++ks)
#pragma unroll
        for (int c = 0; c < 4; ++c)
            breg[ks][c] = Bp[(ks * 8 + wcol * 4 + c) * 64 + lane];

    float bv[4];
#pragma unroll
    for (int c = 0; c < 4; ++c) bv[c] = bias[wcol * 64 + c * 16 + (lane & 15)];

    const uint4* a16 = (const uint4*)agg;   // 8 f16 per uint4; 16 chunks/row
    const uint4* h16 = (const uint4*)h;

    // prologue: stage first tile into buf 0 (1024 x 16B chunks, 4 iters)
    {
        int row0 = blockIdx.x * 32;
#pragma unroll
        for (int it = 0; it < 4; ++it) {
            int i = it * 256 + tid, r = i >> 5, c8 = i & 31;
            uint4 v = (c8 < 16) ? a16[(row0 + r) * 16 + c8]
                                : h16[(row0 + r) * 16 + (c8 - 16)];
            int o = (r * 256 + c8 * 8) ^ ((r & 7) << 3);
            *(uint4*)&sA[0][o] = v;
        }
    }
    __syncthreads();

    int buf = 0;
    for (int t = blockIdx.x; t < N_TILES; t += GEMM_GRID) {
        int  tn = t + GEMM_GRID;
        bool havenext = (tn < N_TILES);

        // issue next tile's global loads early (latency hides under MFMA)
        uint4 sreg[4];
        if (havenext) {
            int row0 = tn * 32;
#pragma unroll
            for (int it = 0; it < 4; ++it) {
                int i = it * 256 + tid, r = i >> 5, c8 = i & 31;
                sreg[it] = (c8 < 16) ? a16[(row0 + r) * 16 + c8]
                                     : h16[(row0 + r) * 16 + (c8 - 16)];
            }
        }

        // compute tile t from sA[buf]
        f32x4 acc[4] = {f32x4{0,0,0,0}, f32x4{0,0,0,0}, f32x4{0,0,0,0}, f32x4{0,0,0,0}};
        int arow = wrow * 16 + (lane & 15);
        int kg   = (lane >> 4) * 8;
#pragma unroll
        for (int ks = 0; ks < 8; ++ks) {
            int o = (arow * 256 + ks * 32 + kg) ^ ((arow & 7) << 3);
            f16x8 afrag = *(const f16x8*)&sA[buf][o];
#pragma unroll
            for (int c = 0; c < 4; ++c)
                acc[c] = __builtin_amdgcn_mfma_f32_16x16x32_f16(afrag, breg[ks][c],
                                                                acc[c], 0, 0, 0);
        }

        // epilogue: bias (+relu), store C  (C/D map: col=lane&15, row=(lane>>4)*4+r)
        {
            int row0 = t * 32;
#pragma unroll
            for (int c = 0; c < 4; ++c) {
                int col = wcol * 64 + c * 16 + (lane & 15);
#pragma unroll
                for (int r = 0; r < 4; ++r) {
                    int row = row0 + wrow * 16 + (lane >> 4) * 4 + r;
                    float o = acc[c][r] + bv[c];
                    if (FINAL) {
                        ((float*)outp)[(size_t)row * D + col] = o;
                    } else {
                        ((f16*)outp)[(size_t)row * D + col] = (f16)fmaxf(o, 0.f);
                    }
                }
            }
        }

        __syncthreads();   // all waves done reading sA[buf^1] (previous iter)
        if (havenext) {
#pragma unroll
            for (int it = 0; it < 4; ++it) {
                int i = it * 256 + tid, r = i >> 5, c8 = i & 31;
                int o = (r * 256 + c8 * 8) ^ ((r & 7) << 3);
                *(uint4*)&sA[buf ^ 1][o] = sreg[it];
            }
        }
        __syncthreads();
        buf ^= 1;
    }
}

// ---------------- launch ----------------

extern "C" void kernel_launch(void* const* d_in, const int* in_sizes, int n_in,
                              void* d_out, int out_size, void* d_ws, size_t ws_size,
                              hipStream_t stream) {
    const float* x  = (const float*)d_in[0];
    const float* ew = (const float*)d_in[1];
    const float* W_rel[3]  = {(const float*)d_in[2], (const float*)d_in[5], (const float*)d_in[8]};
    const float* W_root[3] = {(const float*)d_in[3], (const float*)d_in[6], (const float*)d_in[9]};
    const float* bias[3]   = {(const float*)d_in[4], (const float*)d_in[7], (const float*)d_in[10]};
    const int* esrc = (const int*)d_in[11];
    const int* edst = (const int*)d_in[12];

    char* ws = (char*)d_ws;
    f16*      agg16   = (f16*)     (ws);               // 25,600,000 B
    f16*      bufA    = (f16*)     (ws + 25600000);    // 25,600,000 B
    f16*      bufB    = (f16*)     (ws + 51200000);    // 25,600,000 B
    unsigned* csr     = (unsigned*)(ws + 76800000);    //  6,400,000 B
    int2*     bkt     = (int2*)    (ws + 83200000);    // 16,015,360 B (391 x 5120 x 8)
    int*      row_ptr = (int*)     (ws + 99215360);    //    400,016 B
    int*      bcur    = (int*)     (ws + 99615376);    //      1,564 B
    int*      bbase   = (int*)     (ws + 99616940);    //      1,564 B
    f16*      Bp      = (f16*)     (ws + 99618504);    //    196,608 B

    // CSR build (bucket-based; reused by all 3 layers)
    hipMemsetAsync(bcur, 0, N_BUCKETS * sizeof(int), stream);
    bucket_scatter<<<SC_BLOCKS, 256, 0, stream>>>(esrc, edst, ew, bcur, bkt);
    bucket_scan<<<1, 512, 0, stream>>>(bcur, bbase);
    bucket_finalize<<<N_BUCKETS, 256, 0, stream>>>(bcur, bbase, bkt, csr, row_ptr);

    // x -> f16, weight packs
    cvt_f32_f16<<<6250, 256, 0, stream>>>(x, bufA);
    for (int l = 0; l < 3; ++l)
        pack_weights<<<128, 256, 0, stream>>>(W_rel[l], W_root[l], Bp + l * 32768);

    // layer 0: bufA -> bufB (f16, relu)
    aggregate_kernel<<<N_NODES / 4, 256, 0, stream>>>(bufA, row_ptr, csr, agg16);
    gemm_mfma<0><<<GEMM_GRID, 256, 0, stream>>>(agg16, bufA, (const f16x8*)(Bp + 0 * 32768),
                                                bias[0], bufB);
    // layer 1: bufB -> bufA (f16, relu)
    aggregate_kernel<<<N_NODES / 4, 256, 0, stream>>>(bufB, row_ptr, csr, agg16);
    gemm_mfma<0><<<GEMM_GRID, 256, 0, stream>>>(agg16, bufB, (const f16x8*)(Bp + 1 * 32768),
                                                bias[1], bufA);
    // layer 2: bufA -> d_out (fp32, no relu)
    aggregate_kernel<<<N_NODES / 4, 256, 0, stream>>>(bufA, row_ptr, csr, agg16);
    gemm_mfma<1><<<GEMM_GRID, 256, 0, stream>>>(agg16, bufA, (const f16x8*)(Bp + 2 * 32768),
                                                bias[2], d_out);
}

// Round 11
// 311.150 us; speedup vs baseline: 1.0946x; 1.0123x over previous
//
#include <hip/hip_runtime.h>

#define N_NODES 100000
#define N_EDGES 1600000
#define D 128
#define N_TILES 3125        // N_NODES / 32
#define GEMM_GRID 512
#define BK_NODES 256        // nodes per bucket
#define N_BUCKETS 391       // ceil(N_NODES / BK_NODES)
#define BKT_CAP 5120        // per-bucket slot capacity (mean 4092, std 64 -> 16 sigma)
#define SC_BLOCKS 128
#define EPB 12500           // edges per scatter block (N_EDGES / SC_BLOCKS)
#define SRC_TILES 16
#define SRC_TILE_SZ 6250    // nodes per src-tile (1.6 MB of f16 h -> L2-resident)

typedef _Float16 f16;
typedef _Float16 f16x8 __attribute__((ext_vector_type(8)));
typedef _Float16 f16x2 __attribute__((ext_vector_type(2)));
typedef float f32x4 __attribute__((ext_vector_type(4)));

// f16 bit pattern of w in [0,1] fits in 15 bits (max 0x3C00 = 1.0)
__device__ __forceinline__ unsigned f16bits(float x) {
    union { f16 h; unsigned short u; } c;
    c.h = (f16)x;
    return (unsigned)c.u;
}

// ---------------- CSR build (bucket-based, no per-node global atomics) ----------------

// pass 1: block-local bucket scatter. LDS histogram -> ONE global atomic per
// (block,bucket) reservation (chain length = SC_BLOCKS) -> LDS-cursor placement
// into fixed-capacity bucket slots. Afterwards bcur[b] == bucket edge count.
__global__ __launch_bounds__(256) void bucket_scatter(const int* __restrict__ src,
                                                      const int* __restrict__ dst,
                                                      const float* __restrict__ w,
                                                      int* __restrict__ bcur,
                                                      int2* __restrict__ bkt) {
    __shared__ int hist[N_BUCKETS];
    __shared__ int base[N_BUCKETS];
    int tid = threadIdx.x;
    int v0  = blockIdx.x * (EPB / 4);        // int4-chunk base
    const int4*   dst4 = (const int4*)dst;
    const int4*   src4 = (const int4*)src;
    const float4* w4   = (const float4*)w;

    for (int b = tid; b < N_BUCKETS; b += 256) hist[b] = 0;
    __syncthreads();

    // phase A: count buckets (vectorized dst reads)
    for (int v = tid; v < EPB / 4; v += 256) {
        int4 d = dst4[v0 + v];
        atomicAdd(&hist[d.x >> 8], 1);
        atomicAdd(&hist[d.y >> 8], 1);
        atomicAdd(&hist[d.z >> 8], 1);
        atomicAdd(&hist[d.w >> 8], 1);
    }
    __syncthreads();

    // phase B: reserve within-bucket ranges (bcur starts at 0)
    for (int b = tid; b < N_BUCKETS; b += 256) {
        int c = hist[b];
        base[b] = b * BKT_CAP + ((c > 0) ? atomicAdd(&bcur[b], c) : 0);
        hist[b] = 0;
    }
    __syncthreads();

    // phase C: place edges densely inside reserved ranges (meta = dst<<15 | f16(w))
    for (int v = tid; v < EPB / 4; v += 256) {
        int4   d = dst4[v0 + v];
        int4   s = src4[v0 + v];
        float4 f = w4[v0 + v];
        {
            int p = base[d.x >> 8] + atomicAdd(&hist[d.x >> 8], 1);
            bkt[p] = make_int2(s.x, (int)(((unsigned)d.x << 15) | f16bits(f.x)));
        }
        {
            int p = base[d.y >> 8] + atomicAdd(&hist[d.y >> 8], 1);
            bkt[p] = make_int2(s.y, (int)(((unsigned)d.y << 15) | f16bits(f.y)));
        }
        {
            int p = base[d.z >> 8] + atomicAdd(&hist[d.z >> 8], 1);
            bkt[p] = make_int2(s.z, (int)(((unsigned)d.z << 15) | f16bits(f.z)));
        }
        {
            int p = base[d.w >> 8] + atomicAdd(&hist[d.w >> 8], 1);
            bkt[p] = make_int2(s.w, (int)(((unsigned)d.w << 15) | f16bits(f.w)));
        }
    }
}

// exclusive scan over the 391 bucket counts -> bucket CSR bases (one block)
__global__ __launch_bounds__(512) void bucket_scan(const int* __restrict__ bcnt,
                                                   int* __restrict__ bbase) {
    __shared__ int sc[512];
    int tid = threadIdx.x;
    int v = (tid < N_BUCKETS) ? bcnt[tid] : 0;
    sc[tid] = v;
    __syncthreads();
    for (int off = 1; off < 512; off <<= 1) {
        int t = (tid >= off) ? sc[tid - off] : 0;
        __syncthreads();
        sc[tid] += t;
        __syncthreads();
    }
    if (tid < N_BUCKETS) bbase[tid] = sc[tid] - v;
}

// pass 2: one block per bucket. Places each node's edges SORTED BY SRC-TILE
// (16 tiles x 6250 nodes): within-node order is free (sum), and src-ascending
// order makes concurrent waves' gathers convoy through an L2-resident window.
// LDS cnt[node][tile] -> per-node tile prefix (thread=node) -> absolute bases.
// csr[p] = (src << 15) | f16(w).
__global__ __launch_bounds__(256) void bucket_finalize(const int* __restrict__ bcnt,
                                                       const int* __restrict__ bbase,
                                                       const int2* __restrict__ bkt,
                                                       unsigned* __restrict__ csr,
                                                       int* __restrict__ row_ptr) {
    __shared__ int cnt[BK_NODES * SRC_TILES];   // counts -> absolute placement cursors
    __shared__ int sc[BK_NODES];
    int tid   = threadIdx.x;
    int b     = blockIdx.x;
    int node0 = b * BK_NODES;
    int cntE  = bcnt[b];
    int base  = bbase[b];
    int e0    = b * BKT_CAP;

    for (int i = tid; i < BK_NODES * SRC_TILES; i += 256) cnt[i] = 0;
    __syncthreads();
    for (int i = tid; i < cntE; i += 256) {
        int2 t = bkt[e0 + i];
        int local = (int)((unsigned)t.y >> 15) - node0;
        int tile  = (unsigned)t.x / SRC_TILE_SZ;
        atomicAdd(&cnt[local * SRC_TILES + tile], 1);
    }
    __syncthreads();
    // thread tid owns node tid: per-node prefix over tiles + node total
    int pref[SRC_TILES];
    int run = 0;
#pragma unroll
    for (int t = 0; t < SRC_TILES; ++t) {
        pref[t] = run;
        run += cnt[tid * SRC_TILES + t];
    }
    // block exclusive scan of node totals
    sc[tid] = run;
    __syncthreads();
    for (int off = 1; off < 256; off <<= 1) {
        int t = (tid >= off) ? sc[tid - off] : 0;
        __syncthreads();
        sc[tid] += t;
        __syncthreads();
    }
    int noff = sc[tid] - run;   // exclusive prefix of this node within bucket
    {
        int nN = N_NODES - node0; if (nN > BK_NODES) nN = BK_NODES;
        if (tid < nN) row_ptr[node0 + tid] = base + noff;
        if (b == N_BUCKETS - 1 && tid == 0) row_ptr[N_NODES] = N_EDGES;
    }
    __syncthreads();
#pragma unroll
    for (int t = 0; t < SRC_TILES; ++t)
        cnt[tid * SRC_TILES + t] = base + noff + pref[t];   // absolute cursors
    __syncthreads();
    for (int i = tid; i < cntE; i += 256) {
        int2 t = bkt[e0 + i];
        unsigned meta = (unsigned)t.y;
        int local = (int)(meta >> 15) - node0;
        int tile  = (unsigned)t.x / SRC_TILE_SZ;
        int p = atomicAdd(&cnt[local * SRC_TILES + tile], 1);
        csr[p] = ((unsigned)t.x << 15) | (meta & 0x7fffu);
    }
}

// ---------------- fp32 -> f16 convert (x only, once) ----------------

__global__ __launch_bounds__(256) void cvt_f32_f16(const float* __restrict__ in,
                                                   f16* __restrict__ out) {
    int i = blockIdx.x * 256 + threadIdx.x;   // grid 6250: 8 elems/thread
    const float4* in4 = (const float4*)in;
    float4 a = in4[i * 2], b = in4[i * 2 + 1];
    f16x8 v;
    v[0] = (f16)a.x; v[1] = (f16)a.y; v[2] = (f16)a.z; v[3] = (f16)a.w;
    v[4] = (f16)b.x; v[5] = (f16)b.y; v[6] = (f16)b.z; v[7] = (f16)b.w;
    ((f16x8*)out)[i] = v;
}

// ---------------- weight pack: B-fragment layout, f16 ----------------
// Bp element ((ks*8 + ct)*64 + lane)*8 + e = W[j][k] with
// j = ct*16 + (lane&15), k = ks*32 + (lane>>4)*8 + e  (k<128 -> Wrel, else Wroot)

__global__ __launch_bounds__(256) void pack_weights(const float* __restrict__ Wrel,
                                                    const float* __restrict__ Wroot,
                                                    f16* __restrict__ Bp) {
    int idx = blockIdx.x * 256 + threadIdx.x;   // 32768 total -> 128 blocks
    int e = idx & 7, lane = (idx >> 3) & 63, ct = (idx >> 9) & 7, ks = idx >> 12;
    int j = ct * 16 + (lane & 15);
    int k = ks * 32 + (lane >> 4) * 8 + e;
    float w = (k < D) ? Wrel[j * D + k] : Wroot[j * D + (k - D)];
    Bp[idx] = (f16)w;
}

// ---------------- aggregation: one wave/node, readlane CSR, pk_fma f16 ----------------
// csr word = (src<<15) | f16bits(w). Decode is pure SALU on the readlane result;
// per-edge VALU = 1 readlane + 1 v_pk_fma_f16. Tail CLAMPS (duplicate-address
// gathers broadcast-coalesce to one line: memory-free) with weight forced to 0.
// Edge lists are src-tile-sorted -> gathers convoy through an L2-resident window.

__global__ __launch_bounds__(256) void aggregate_kernel(const f16* __restrict__ h,
                                                        const int* __restrict__ row_ptr,
                                                        const unsigned* __restrict__ csr,
                                                        f16* __restrict__ agg) {
    int node = blockIdx.x * 4 + (threadIdx.x >> 6);   // grid*4 == N_NODES exactly
    int lane = threadIdx.x & 63;
    int li   = lane & 15;
    int beg = row_ptr[node], end = row_ptr[node + 1];
    const f16x2* h2 = (const f16x2*)h;   // lane covers channels 2l, 2l+1

    f16x2 acc0 = {(f16)0.f, (f16)0.f};
    f16x2 acc1 = {(f16)0.f, (f16)0.f};

    int e = beg;
    for (; e + 16 <= end; e += 16) {
        // lanes 0-15 fetch 16 packed edges in one 64B line (quarters duplicate)
        unsigned pv = csr[e + li];
        __builtin_amdgcn_sched_barrier(0);
        f16x2    gv[16];
        unsigned wm[16];
#pragma unroll
        for (int k = 0; k < 16; ++k) {
            unsigned s = __builtin_amdgcn_readlane(pv, k);   // uniform -> SGPR
            wm[k] = s & 0x7fffu;                             // f16 bits of w (SALU)
            gv[k] = h2[(size_t)(s >> 15) * 64 + lane];       // saddr gather, 256B/wave
        }
        __builtin_amdgcn_sched_barrier(0);   // keep all 16 gathers in flight
#pragma unroll
        for (int k = 0; k < 16; ++k) {
            union { unsigned u; f16x2 v; } wc;
            wc.u = wm[k] * 0x10001u;         // duplicate f16 into both halves (SALU)
            if (k & 1) acc1 += gv[k] * wc.v; // v_pk_fma_f16
            else       acc0 += gv[k] * wc.v;
        }
    }
    if (e < end) {   // clamped tail: dead lanes re-read one line (broadcast), w=0
        int rem = end - e;                   // 1..15
        int idx = e + li, em1 = end - 1;
        idx = idx < em1 ? idx : em1;
        unsigned pv = csr[idx];
        __builtin_amdgcn_sched_barrier(0);
        f16x2    gv[16];
        unsigned wm[16];
#pragma unroll
        for (int k = 0; k < 16; ++k) {
            unsigned s = __builtin_amdgcn_readlane(pv, k);
            s = (k < rem) ? s : 0u;          // wave-uniform select (SALU)
            wm[k] = s & 0x7fffu;
            gv[k] = h2[(size_t)(s >> 15) * 64 + lane];
        }
        __builtin_amdgcn_sched_barrier(0);
#pragma unroll
        for (int k = 0; k < 16; ++k) {
            union { unsigned u; f16x2 v; } wc;
            wc.u = wm[k] * 0x10001u;
            if (k & 1) acc1 += gv[k] * wc.v;
            else       acc0 += gv[k] * wc.v;
        }
    }
    ((f16x2*)agg)[(size_t)node * 64 + lane] = acc0 + acc1;
}

// ---------------- MFMA GEMM: out = [agg|h] @ Bp + bias (+ReLU) ----------------
// 256 thr = 4 waves (2 row x 2 col). Wave owns 16 rows x 64 cols.
// B-frags in registers. A (f16) staged in LDS, XOR-swizzled, double-buffered.
// FINAL=0: f16 out + ReLU.  FINAL=1: fp32 out, no ReLU.

template <int FINAL>
__global__ __launch_bounds__(256, 2) void gemm_mfma(const f16* __restrict__ agg,
                                                    const f16* __restrict__ h,
                                                    const f16x8* __restrict__ Bp,
                                                    const float* __restrict__ bias,
                                                    void* __restrict__ outp) {
    __shared__ f16 sA[2][32 * 256];   // 2 x 16 KB
    int tid  = threadIdx.x;
    int lane = tid & 63;
    int wid  = tid >> 6;
    int wrow = wid >> 1;              // rows [wrow*16, +16)
    int wcol = wid & 1;               // cols [wcol*64, +64)

    // B fragments: 8 k-steps x 4 col-tiles, loaded once (L2-hot)
    f16x8 breg[8][4];
#pragma unroll
    for (int ks = 0; ks < 8; ++ks)
#pragma unroll
        for (int c = 0; c < 4; ++c)
            breg[ks][c] = Bp[(ks * 8 + wcol * 4 + c) * 64 + lane];

    float bv[4];
#pragma unroll
    for (int c = 0; c < 4; ++c) bv[c] = bias[wcol * 64 + c * 16 + (lane & 15)];

    const uint4* a16 = (const uint4*)agg;   // 8 f16 per uint4; 16 chunks/row
    const uint4* h16 = (const uint4*)h;

    // prologue: stage first tile into buf 0 (1024 x 16B chunks, 4 iters)
    {
        int row0 = blockIdx.x * 32;
#pragma unroll
        for (int it = 0; it < 4; ++it) {
            int i = it * 256 + tid, r = i >> 5, c8 = i & 31;
            uint4 v = (c8 < 16) ? a16[(row0 + r) * 16 + c8]
                                : h16[(row0 + r) * 16 + (c8 - 16)];
            int o = (r * 256 + c8 * 8) ^ ((r & 7) << 3);
            *(uint4*)&sA[0][o] = v;
        }
    }
    __syncthreads();

    int buf = 0;
    for (int t = blockIdx.x; t < N_TILES; t += GEMM_GRID) {
        int  tn = t + GEMM_GRID;
        bool havenext = (tn < N_TILES);

        // issue next tile's global loads early (latency hides under MFMA)
        uint4 sreg[4];
        if (havenext) {
            int row0 = tn * 32;
#pragma unroll
            for (int it = 0; it < 4; ++it) {
                int i = it * 256 + tid, r = i >> 5, c8 = i & 31;
                sreg[it] = (c8 < 16) ? a16[(row0 + r) * 16 + c8]
                                     : h16[(row0 + r) * 16 + (c8 - 16)];
            }
        }

        // compute tile t from sA[buf]
        f32x4 acc[4] = {f32x4{0,0,0,0}, f32x4{0,0,0,0}, f32x4{0,0,0,0}, f32x4{0,0,0,0}};
        int arow = wrow * 16 + (lane & 15);
        int kg   = (lane >> 4) * 8;
#pragma unroll
        for (int ks = 0; ks < 8; ++ks) {
            int o = (arow * 256 + ks * 32 + kg) ^ ((arow & 7) << 3);
            f16x8 afrag = *(const f16x8*)&sA[buf][o];
#pragma unroll
            for (int c = 0; c < 4; ++c)
                acc[c] = __builtin_amdgcn_mfma_f32_16x16x32_f16(afrag, breg[ks][c],
                                                                acc[c], 0, 0, 0);
        }

        // epilogue: bias (+relu), store C  (C/D map: col=lane&15, row=(lane>>4)*4+r)
        {
            int row0 = t * 32;
#pragma unroll
            for (int c = 0; c < 4; ++c) {
                int col = wcol * 64 + c * 16 + (lane & 15);
#pragma unroll
                for (int r = 0; r < 4; ++r) {
                    int row = row0 + wrow * 16 + (lane >> 4) * 4 + r;
                    float o = acc[c][r] + bv[c];
                    if (FINAL) {
                        ((float*)outp)[(size_t)row * D + col] = o;
                    } else {
                        ((f16*)outp)[(size_t)row * D + col] = (f16)fmaxf(o, 0.f);
                    }
                }
            }
        }

        __syncthreads();   // all waves done reading sA[buf^1] (previous iter)
        if (havenext) {
#pragma unroll
            for (int it = 0; it < 4; ++it) {
                int i = it * 256 + tid, r = i >> 5, c8 = i & 31;
                int o = (r * 256 + c8 * 8) ^ ((r & 7) << 3);
                *(uint4*)&sA[buf ^ 1][o] = sreg[it];
            }
        }
        __syncthreads();
        buf ^= 1;
    }
}

// ---------------- launch ----------------

extern "C" void kernel_launch(void* const* d_in, const int* in_sizes, int n_in,
                              void* d_out, int out_size, void* d_ws, size_t ws_size,
                              hipStream_t stream) {
    const float* x  = (const float*)d_in[0];
    const float* ew = (const float*)d_in[1];
    const float* W_rel[3]  = {(const float*)d_in[2], (const float*)d_in[5], (const float*)d_in[8]};
    const float* W_root[3] = {(const float*)d_in[3], (const float*)d_in[6], (const float*)d_in[9]};
    const float* bias[3]   = {(const float*)d_in[4], (const float*)d_in[7], (const float*)d_in[10]};
    const int* esrc = (const int*)d_in[11];
    const int* edst = (const int*)d_in[12];

    char* ws = (char*)d_ws;
    f16*      agg16   = (f16*)     (ws);               // 25,600,000 B
    f16*      bufA    = (f16*)     (ws + 25600000);    // 25,600,000 B
    f16*      bufB    = (f16*)     (ws + 51200000);    // 25,600,000 B
    unsigned* csr     = (unsigned*)(ws + 76800000);    //  6,400,000 B
    int2*     bkt     = (int2*)    (ws + 83200000);    // 16,015,360 B (391 x 5120 x 8)
    int*      row_ptr = (int*)     (ws + 99215360);    //    400,016 B
    int*      bcur    = (int*)     (ws + 99615376);    //      1,564 B
    int*      bbase   = (int*)     (ws + 99616940);    //      1,564 B
    f16*      Bp      = (f16*)     (ws + 99618504);    //    196,608 B

    // CSR build (bucket-based; reused by all 3 layers)
    hipMemsetAsync(bcur, 0, N_BUCKETS * sizeof(int), stream);
    bucket_scatter<<<SC_BLOCKS, 256, 0, stream>>>(esrc, edst, ew, bcur, bkt);
    bucket_scan<<<1, 512, 0, stream>>>(bcur, bbase);
    bucket_finalize<<<N_BUCKETS, 256, 0, stream>>>(bcur, bbase, bkt, csr, row_ptr);

    // x -> f16, weight packs
    cvt_f32_f16<<<6250, 256, 0, stream>>>(x, bufA);
    for (int l = 0; l < 3; ++l)
        pack_weights<<<128, 256, 0, stream>>>(W_rel[l], W_root[l], Bp + l * 32768);

    // layer 0: bufA -> bufB (f16, relu)
    aggregate_kernel<<<N_NODES / 4, 256, 0, stream>>>(bufA, row_ptr, csr, agg16);
    gemm_mfma<0><<<GEMM_GRID, 256, 0, stream>>>(agg16, bufA, (const f16x8*)(Bp + 0 * 32768),
                                                bias[0], bufB);
    // layer 1: bufB -> bufA (f16, relu)
    aggregate_kernel<<<N_NODES / 4, 256, 0, stream>>>(bufB, row_ptr, csr, agg16);
    gemm_mfma<0><<<GEMM_GRID, 256, 0, stream>>>(agg16, bufB, (const f16x8*)(Bp + 1 * 32768),
                                                bias[1], bufA);
    // layer 2: bufA -> d_out (fp32, no relu)
    aggregate_kernel<<<N_NODES / 4, 256, 0, stream>>>(bufA, row_ptr, csr, agg16);
    gemm_mfma<1><<<GEMM_GRID, 256, 0, stream>>>(agg16, bufA, (const f16x8*)(Bp + 2 * 32768),
                                                bias[2], d_out);
}

// Round 12
// 276.791 us; speedup vs baseline: 1.2305x; 1.1241x over previous
//
#include <hip/hip_runtime.h>

#define N_NODES 100000
#define N_EDGES 1600000
#define D 128
#define GEMM_GRID 3125      // one block per 32-row tile
#define BK_NODES 256        // nodes per bucket
#define N_BUCKETS 391       // ceil(N_NODES / BK_NODES)
#define BKT_CAP 5120        // per-bucket slot capacity (mean 4092, std 64 -> 16 sigma)
#define SC_BLOCKS 128
#define EPB 12500           // edges per scatter block (N_EDGES / SC_BLOCKS)

typedef _Float16 f16;
typedef _Float16 f16x8 __attribute__((ext_vector_type(8)));
typedef _Float16 f16x2 __attribute__((ext_vector_type(2)));
typedef float f32x4 __attribute__((ext_vector_type(4)));

// f16 bit pattern of w in [0,1] fits in 15 bits (max 0x3C00 = 1.0)
__device__ __forceinline__ unsigned f16bits(float x) {
    union { f16 h; unsigned short u; } c;
    c.h = (f16)x;
    return (unsigned)c.u;
}

// ---------------- CSR build (bucket-based, no per-node global atomics) ----------------

__global__ __launch_bounds__(256) void bucket_scatter(const int* __restrict__ src,
                                                      const int* __restrict__ dst,
                                                      const float* __restrict__ w,
                                                      int* __restrict__ bcur,
                                                      int2* __restrict__ bkt) {
    __shared__ int hist[N_BUCKETS];
    __shared__ int base[N_BUCKETS];
    int tid = threadIdx.x;
    int v0  = blockIdx.x * (EPB / 4);        // int4-chunk base
    const int4*   dst4 = (const int4*)dst;
    const int4*   src4 = (const int4*)src;
    const float4* w4   = (const float4*)w;

    for (int b = tid; b < N_BUCKETS; b += 256) hist[b] = 0;
    __syncthreads();

    // phase A: count buckets (vectorized dst reads)
    for (int v = tid; v < EPB / 4; v += 256) {
        int4 d = dst4[v0 + v];
        atomicAdd(&hist[d.x >> 8], 1);
        atomicAdd(&hist[d.y >> 8], 1);
        atomicAdd(&hist[d.z >> 8], 1);
        atomicAdd(&hist[d.w >> 8], 1);
    }
    __syncthreads();

    // phase B: reserve within-bucket ranges (bcur starts at 0)
    for (int b = tid; b < N_BUCKETS; b += 256) {
        int c = hist[b];
        base[b] = b * BKT_CAP + ((c > 0) ? atomicAdd(&bcur[b], c) : 0);
        hist[b] = 0;
    }
    __syncthreads();

    // phase C: place edges densely inside reserved ranges (meta = dst<<15 | f16(w))
    for (int v = tid; v < EPB / 4; v += 256) {
        int4   d = dst4[v0 + v];
        int4   s = src4[v0 + v];
        float4 f = w4[v0 + v];
        {
            int p = base[d.x >> 8] + atomicAdd(&hist[d.x >> 8], 1);
            bkt[p] = make_int2(s.x, (int)(((unsigned)d.x << 15) | f16bits(f.x)));
        }
        {
            int p = base[d.y >> 8] + atomicAdd(&hist[d.y >> 8], 1);
            bkt[p] = make_int2(s.y, (int)(((unsigned)d.y << 15) | f16bits(f.y)));
        }
        {
            int p = base[d.z >> 8] + atomicAdd(&hist[d.z >> 8], 1);
            bkt[p] = make_int2(s.z, (int)(((unsigned)d.z << 15) | f16bits(f.z)));
        }
        {
            int p = base[d.w >> 8] + atomicAdd(&hist[d.w >> 8], 1);
            bkt[p] = make_int2(s.w, (int)(((unsigned)d.w << 15) | f16bits(f.w)));
        }
    }
}

// exclusive scan over the 391 bucket counts -> bucket CSR bases (one block)
__global__ __launch_bounds__(512) void bucket_scan(const int* __restrict__ bcnt,
                                                   int* __restrict__ bbase) {
    __shared__ int sc[512];
    int tid = threadIdx.x;
    int v = (tid < N_BUCKETS) ? bcnt[tid] : 0;
    sc[tid] = v;
    __syncthreads();
    for (int off = 1; off < 512; off <<= 1) {
        int t = (tid >= off) ? sc[tid - off] : 0;
        __syncthreads();
        sc[tid] += t;
        __syncthreads();
    }
    if (tid < N_BUCKETS) bbase[tid] = sc[tid] - v;
}

// pass 2: one block per bucket. LDS node histogram + block scan -> row_ptr AND
// final csr placement (dense contiguous writes). csr[p] = (src << 15) | f16(w).
__global__ __launch_bounds__(256) void bucket_finalize(const int* __restrict__ bcnt,
                                                       const int* __restrict__ bbase,
                                                       const int2* __restrict__ bkt,
                                                       unsigned* __restrict__ csr,
                                                       int* __restrict__ row_ptr) {
    __shared__ int ncnt[BK_NODES];
    __shared__ int noff[BK_NODES];
    __shared__ int sc[BK_NODES];
    int tid   = threadIdx.x;
    int b     = blockIdx.x;
    int node0 = b * BK_NODES;
    int cnt   = bcnt[b];
    int base  = bbase[b];
    int e0    = b * BKT_CAP;

    ncnt[tid] = 0;
    __syncthreads();
    for (int i = tid; i < cnt; i += 256) {
        int local = (int)((unsigned)bkt[e0 + i].y >> 15) - node0;
        atomicAdd(&ncnt[local], 1);
    }
    __syncthreads();
    int s = ncnt[tid];
    sc[tid] = s;
    __syncthreads();
    for (int off = 1; off < 256; off <<= 1) {
        int t = (tid >= off) ? sc[tid - off] : 0;
        __syncthreads();
        sc[tid] += t;
        __syncthreads();
    }
    noff[tid] = sc[tid] - s;
    ncnt[tid] = 0;   // reuse as placement cursor
    {
        int nN = N_NODES - node0; if (nN > BK_NODES) nN = BK_NODES;
        if (tid < nN) row_ptr[node0 + tid] = base + noff[tid];
        if (b == N_BUCKETS - 1 && tid == 0) row_ptr[N_NODES] = N_EDGES;
    }
    __syncthreads();
    for (int i = tid; i < cnt; i += 256) {
        int2 t = bkt[e0 + i];
        unsigned meta = (unsigned)t.y;
        int local = (int)(meta >> 15) - node0;
        int p = base + noff[local] + atomicAdd(&ncnt[local], 1);
        csr[p] = ((unsigned)t.x << 15) | (meta & 0x7fffu);
    }
}

// ---------------- fp32 -> f16 convert (x only, once) ----------------

__global__ __launch_bounds__(256) void cvt_f32_f16(const float* __restrict__ in,
                                                   f16* __restrict__ out) {
    int i = blockIdx.x * 256 + threadIdx.x;   // grid 6250: 8 elems/thread
    const float4* in4 = (const float4*)in;
    float4 a = in4[i * 2], b = in4[i * 2 + 1];
    f16x8 v;
    v[0] = (f16)a.x; v[1] = (f16)a.y; v[2] = (f16)a.z; v[3] = (f16)a.w;
    v[4] = (f16)b.x; v[5] = (f16)b.y; v[6] = (f16)b.z; v[7] = (f16)b.w;
    ((f16x8*)out)[i] = v;
}

// ---------------- weight pack: B-fragment layout, f16 ----------------
// Bp element ((ks*8 + ct)*64 + lane)*8 + e = W[j][k] with
// j = ct*16 + (lane&15), k = ks*32 + (lane>>4)*8 + e  (k<128 -> Wrel, else Wroot)

__global__ __launch_bounds__(256) void pack_weights(const float* __restrict__ Wrel,
                                                    const float* __restrict__ Wroot,
                                                    f16* __restrict__ Bp) {
    int idx = blockIdx.x * 256 + threadIdx.x;   // 32768 total -> 128 blocks
    int e = idx & 7, lane = (idx >> 3) & 63, ct = (idx >> 9) & 7, ks = idx >> 12;
    int j = ct * 16 + (lane & 15);
    int k = ks * 32 + (lane >> 4) * 8 + e;
    float w = (k < D) ? Wrel[j * D + k] : Wroot[j * D + (k - D)];
    Bp[idx] = (f16)w;
}

// ---------------- FUSED layer: aggregate (into LDS) + MFMA GEMM ----------------
// One block per 32-node tile. Phase 1: 4 waves aggregate 8 nodes each
// (readlane CSR, 16-deep pinned gathers, pk_fma f16) writing f16x2 results
// straight into the swizzled LDS A-tile cols 0-127; h rows staged to cols
// 128-255. Phase 2: MFMA with B streamed from L2 (1-deep pipeline, low VGPR
// so phase-1 gather occupancy stays high). FINAL=0: f16 out + ReLU. 1: fp32.

template <int FINAL>
__global__ __launch_bounds__(256) void fused_layer(const f16* __restrict__ h,
                                                   const int* __restrict__ row_ptr,
                                                   const unsigned* __restrict__ csr,
                                                   const f16x8* __restrict__ Bp,
                                                   const float* __restrict__ bias,
                                                   void* __restrict__ outp) {
    __shared__ f16 sA[32 * 256];   // 16 KB: [row][k] k<128 agg, k>=128 h (XOR swz)
    int tid  = threadIdx.x;
    int lane = tid & 63;
    int wid  = tid >> 6;
    int li   = lane & 15;
    int node0 = blockIdx.x * 32;
    const f16x2* h2  = (const f16x2*)h;
    const uint4* h16 = (const uint4*)h;

    // ---- phase 1a: aggregate 8 nodes per wave into LDS ----
    for (int n = 0; n < 8; ++n) {
        int row  = wid * 8 + n;
        int node = node0 + row;
        int beg = row_ptr[node], end = row_ptr[node + 1];

        f16x2 acc0 = {(f16)0.f, (f16)0.f};
        f16x2 acc1 = {(f16)0.f, (f16)0.f};

        int e = beg;
        for (; e + 16 <= end; e += 16) {
            unsigned pv = csr[e + li];
            __builtin_amdgcn_sched_barrier(0);
            f16x2    gv[16];
            unsigned wm[16];
#pragma unroll
            for (int k = 0; k < 16; ++k) {
                unsigned s = __builtin_amdgcn_readlane(pv, k);   // uniform -> SGPR
                wm[k] = s & 0x7fffu;
                gv[k] = h2[(size_t)(s >> 15) * 64 + lane];       // 256B/wave gather
            }
            __builtin_amdgcn_sched_barrier(0);   // keep all 16 gathers in flight
#pragma unroll
            for (int k = 0; k < 16; ++k) {
                union { unsigned u; f16x2 v; } wc;
                wc.u = wm[k] * 0x10001u;
                if (k & 1) acc1 += gv[k] * wc.v;
                else       acc0 += gv[k] * wc.v;
            }
        }
        if (e < end) {   // clamped tail: duplicate-addr gathers broadcast, w=0
            int rem = end - e;
            int idx = e + li, em1 = end - 1;
            idx = idx < em1 ? idx : em1;
            unsigned pv = csr[idx];
            __builtin_amdgcn_sched_barrier(0);
            f16x2    gv[16];
            unsigned wm[16];
#pragma unroll
            for (int k = 0; k < 16; ++k) {
                unsigned s = __builtin_amdgcn_readlane(pv, k);
                s = (k < rem) ? s : 0u;
                wm[k] = s & 0x7fffu;
                gv[k] = h2[(size_t)(s >> 15) * 64 + lane];
            }
            __builtin_amdgcn_sched_barrier(0);
#pragma unroll
            for (int k = 0; k < 16; ++k) {
                union { unsigned u; f16x2 v; } wc;
                wc.u = wm[k] * 0x10001u;
                if (k & 1) acc1 += gv[k] * wc.v;
                else       acc0 += gv[k] * wc.v;
            }
        }
        int o = (row * 256 + lane * 2) ^ ((row & 7) << 3);
        *(f16x2*)&sA[o] = acc0 + acc1;
    }

    // ---- phase 1b: stage h rows into cols 128-255 (512 uint4 chunks) ----
#pragma unroll
    for (int it = 0; it < 2; ++it) {
        int i = it * 256 + tid, r = i >> 4, c8 = (i & 15) + 16;
        int o = (r * 256 + c8 * 8) ^ ((r & 7) << 3);
        *(uint4*)&sA[o] = h16[(size_t)(node0 + r) * 16 + (c8 - 16)];
    }
    __syncthreads();

    // ---- phase 2: MFMA (wave = 16 rows x 64 cols), B streamed from L2 ----
    int wrow = wid >> 1;
    int wcol = wid & 1;
    float bv[4];
#pragma unroll
    for (int c = 0; c < 4; ++c) bv[c] = bias[wcol * 64 + c * 16 + (lane & 15)];

    f32x4 acc[4] = {f32x4{0,0,0,0}, f32x4{0,0,0,0}, f32x4{0,0,0,0}, f32x4{0,0,0,0}};
    int arow = wrow * 16 + (lane & 15);
    int kg   = (lane >> 4) * 8;

    f16x8 b0 = Bp[(0 * 8 + wcol * 4 + 0) * 64 + lane];
    f16x8 b1 = Bp[(0 * 8 + wcol * 4 + 1) * 64 + lane];
    f16x8 b2 = Bp[(0 * 8 + wcol * 4 + 2) * 64 + lane];
    f16x8 b3 = Bp[(0 * 8 + wcol * 4 + 3) * 64 + lane];
#pragma unroll 1
    for (int ks = 0; ks < 8; ++ks) {
        f16x8 n0, n1, n2, n3;
        if (ks < 7) {   // 1-deep pipeline: issue next B-frags before MFMA
            n0 = Bp[((ks + 1) * 8 + wcol * 4 + 0) * 64 + lane];
            n1 = Bp[((ks + 1) * 8 + wcol * 4 + 1) * 64 + lane];
            n2 = Bp[((ks + 1) * 8 + wcol * 4 + 2) * 64 + lane];
            n3 = Bp[((ks + 1) * 8 + wcol * 4 + 3) * 64 + lane];
        }
        int o = (arow * 256 + ks * 32 + kg) ^ ((arow & 7) << 3);
        f16x8 afrag = *(const f16x8*)&sA[o];
        acc[0] = __builtin_amdgcn_mfma_f32_16x16x32_f16(afrag, b0, acc[0], 0, 0, 0);
        acc[1] = __builtin_amdgcn_mfma_f32_16x16x32_f16(afrag, b1, acc[1], 0, 0, 0);
        acc[2] = __builtin_amdgcn_mfma_f32_16x16x32_f16(afrag, b2, acc[2], 0, 0, 0);
        acc[3] = __builtin_amdgcn_mfma_f32_16x16x32_f16(afrag, b3, acc[3], 0, 0, 0);
        b0 = n0; b1 = n1; b2 = n2; b3 = n3;
    }

    // epilogue: bias (+relu), store C  (C/D map: col=lane&15, row=(lane>>4)*4+r)
#pragma unroll
    for (int c = 0; c < 4; ++c) {
        int col = wcol * 64 + c * 16 + (lane & 15);
#pragma unroll
        for (int r = 0; r < 4; ++r) {
            int row = node0 + wrow * 16 + (lane >> 4) * 4 + r;
            float o = acc[c][r] + bv[c];
            if (FINAL) {
                ((float*)outp)[(size_t)row * D + col] = o;
            } else {
                ((f16*)outp)[(size_t)row * D + col] = (f16)fmaxf(o, 0.f);
            }
        }
    }
}

// ---------------- launch ----------------

extern "C" void kernel_launch(void* const* d_in, const int* in_sizes, int n_in,
                              void* d_out, int out_size, void* d_ws, size_t ws_size,
                              hipStream_t stream) {
    const float* x  = (const float*)d_in[0];
    const float* ew = (const float*)d_in[1];
    const float* W_rel[3]  = {(const float*)d_in[2], (const float*)d_in[5], (const float*)d_in[8]};
    const float* W_root[3] = {(const float*)d_in[3], (const float*)d_in[6], (const float*)d_in[9]};
    const float* bias[3]   = {(const float*)d_in[4], (const float*)d_in[7], (const float*)d_in[10]};
    const int* esrc = (const int*)d_in[11];
    const int* edst = (const int*)d_in[12];

    char* ws = (char*)d_ws;
    f16*      bufA    = (f16*)     (ws);               // 25,600,000 B
    f16*      bufB    = (f16*)     (ws + 25600000);    // 25,600,000 B
    unsigned* csr     = (unsigned*)(ws + 51200000);    //  6,400,000 B
    int2*     bkt     = (int2*)    (ws + 57600000);    // 16,015,360 B (391 x 5120 x 8)
    int*      row_ptr = (int*)     (ws + 73615360);    //    400,016 B
    int*      bcur    = (int*)     (ws + 74015376);    //      1,564 B
    int*      bbase   = (int*)     (ws + 74016940);    //      1,564 B
    f16*      Bp      = (f16*)     (ws + 74018504);    //    196,608 B

    // CSR build (bucket-based; reused by all 3 layers)
    hipMemsetAsync(bcur, 0, N_BUCKETS * sizeof(int), stream);
    bucket_scatter<<<SC_BLOCKS, 256, 0, stream>>>(esrc, edst, ew, bcur, bkt);
    bucket_scan<<<1, 512, 0, stream>>>(bcur, bbase);
    bucket_finalize<<<N_BUCKETS, 256, 0, stream>>>(bcur, bbase, bkt, csr, row_ptr);

    // x -> f16, weight packs
    cvt_f32_f16<<<6250, 256, 0, stream>>>(x, bufA);
    for (int l = 0; l < 3; ++l)
        pack_weights<<<128, 256, 0, stream>>>(W_rel[l], W_root[l], Bp + l * 32768);

    // 3 fused layers: bufA -> bufB -> bufA -> d_out
    fused_layer<0><<<GEMM_GRID, 256, 0, stream>>>(bufA, row_ptr, csr,
                                                  (const f16x8*)(Bp + 0 * 32768),
                                                  bias[0], bufB);
    fused_layer<0><<<GEMM_GRID, 256, 0, stream>>>(bufB, row_ptr, csr,
                                                  (const f16x8*)(Bp + 1 * 32768),
                                                  bias[1], bufA);
    fused_layer<1><<<GEMM_GRID, 256, 0, stream>>>(bufA, row_ptr, csr,
                                                  (const f16x8*)(Bp + 2 * 32768),
                                                  bias[2], d_out);
}